// Round 5
// baseline (270.923 us; speedup 1.0000x reference)
//
#include <hip/hip_runtime.h>

// SmoothGCN: out = ((x@Wn + bn) + (segsum(x[src]*w, dst)@We + be)) @ Wm + bm
// Refactor: y = x@We; h = x@Wn + bn + be; h[dst] += w_e*y[src]; out = h@Wm + bm
// R11: R10's top-5 cutoff (79.7) shows gatherB+gemm2 ~= 145us combined, both
// latency-bound and hard-serialized through an hbf HBM round trip. fuse2:
// block b gathers bins 4b..4b+3 (its own output rows) into the LDS A-tile
// (bf16, XOR-swizzled) and GEMMs it against L2-resident Wmt immediately --
// block-local dependency only, no flags, hbf eliminated. Gather unroll-8
// keeps 8 load chains in flight to cover the lower blocks/CU.

constexpr int N_NODES  = 50000;
constexpr int N_EDGES  = 1600000;
constexpr int IN_FEAT  = 256;
constexpr int HID      = 128;
constexpr int OUT_FEAT = 256;

constexpr int BIN_SZ   = 32;                                // nodes per bin
constexpr int N_BINS   = (N_NODES + BIN_SZ - 1) / BIN_SZ;   // 1563
constexpr int CAPBIN   = 1536;   // mean 1024, multinomial max ~1150, P(>1536)~0
constexpr int EPB      = 4096;   // edges per binC block
constexpr int N_CBLK   = (N_EDGES + EPB - 1) / EPB;         // 391
constexpr int GRID_M   = (N_NODES + 127) / 128;             // 391
constexpr int N_G1BLK  = GRID_M * 2;                        // 782

typedef __attribute__((ext_vector_type(8))) short bf16x8;
typedef __attribute__((ext_vector_type(8))) unsigned short u16x8;
typedef __attribute__((ext_vector_type(4))) float f32x4;

static __device__ __forceinline__ unsigned short f2bf(float f) {
    unsigned u = __builtin_bit_cast(unsigned, f);
    u += 0x7FFF + ((u >> 16) & 1);          // round-to-nearest-even
    return (unsigned short)(u >> 16);
}
static __device__ __forceinline__ float bflo(unsigned u) {
    return __builtin_bit_cast(float, u << 16);
}
static __device__ __forceinline__ float bfhi(unsigned u) {
    return __builtin_bit_cast(float, u & 0xFFFF0000u);
}

// ---------------- k0: transpose+convert weights to bf16 ----------------
__global__ __launch_bounds__(256) void k0_convert(
    const float* __restrict__ Wn, const float* __restrict__ We,
    const float* __restrict__ Wm,
    unsigned short* __restrict__ Wcat_t, unsigned short* __restrict__ Wmt)
{
    int n = blockIdx.x;      // 0..255
    int k = threadIdx.x;     // 0..255
    float v = (n < HID) ? Wn[(size_t)k * HID + n] : We[(size_t)k * HID + (n - HID)];
    Wcat_t[(size_t)n * IN_FEAT + k] = f2bf(v);
    if (k < HID) Wmt[(size_t)n * HID + k] = f2bf(Wm[(size_t)k * OUT_FEAT + n]);
}

// ---------------- fuse1: binC (blocks 0..N_CBLK-1) || gemm1 (rest) --------
union SharedU {
    struct {
        int  hist[N_BINS];
        int  gbase[N_BINS];
        int  wsum[8];
        int  stot;
        int2 sorted[EPB];            // 32 KB
    } bc;                            // ~44.3 KB
    struct {
        unsigned short As[128][64];  // 16 KB
        unsigned short Bs[128][64];  // 16 KB
    } g1;
};

__global__ __launch_bounds__(512, 4) void fuse1(
    const int* __restrict__ src, const int* __restrict__ dst,
    const float* __restrict__ w, int* __restrict__ cursor,
    int2* __restrict__ entries,
    const float* __restrict__ x, const unsigned short* __restrict__ Wcat_t,
    const float* __restrict__ bn, const float* __restrict__ be,
    float* __restrict__ h0, unsigned short* __restrict__ ybf)
{
    __shared__ SharedU sh;
    const int t = threadIdx.x;
    const int wave = t >> 6, lane = t & 63;

    if (blockIdx.x < N_CBLK) {
        // ================= binC role (unchanged logic) =================
        const int e0 = blockIdx.x * EPB;

        for (int i = t; i < N_BINS; i += 512) sh.bc.hist[i] = 0;
        __syncthreads();

        int meta[8], wb[8], rk[8], bin[8];
        #pragma unroll
        for (int k = 0; k < 8; ++k) {
            int e = e0 + t + k * 512;
            bin[k] = -1;
            if (e < N_EDGES) {
                int d = dst[e];
                int b = d >> 5;
                bin[k]  = b;
                meta[k] = src[e] | ((d & 31) << 16) | (b << 21);  // src<65536 ok
                wb[k]   = __float_as_int(w[e]);
                rk[k]   = atomicAdd(&sh.bc.hist[b], 1);
            }
        }
        __syncthreads();

        // block exclusive scan of hist (4 contiguous bins per thread)
        const int b4 = t * 4;
        int c0 = 0, c1 = 0, c2 = 0, c3 = 0;
        if (b4 + 0 < N_BINS) c0 = sh.bc.hist[b4 + 0];
        if (b4 + 1 < N_BINS) c1 = sh.bc.hist[b4 + 1];
        if (b4 + 2 < N_BINS) c2 = sh.bc.hist[b4 + 2];
        if (b4 + 3 < N_BINS) c3 = sh.bc.hist[b4 + 3];
        const int s = c0 + c1 + c2 + c3;
        int pre = s;
        #pragma unroll
        for (int off = 1; off < 64; off <<= 1) {
            int o = __shfl_up(pre, off, 64);
            if (lane >= off) pre += o;
        }
        if (lane == 63) sh.bc.wsum[wave] = pre;
        __syncthreads();
        if (t == 0) {
            int r = 0;
            #pragma unroll
            for (int q = 0; q < 8; ++q) { int v = sh.bc.wsum[q]; sh.bc.wsum[q] = r; r += v; }
            sh.bc.stot = r;
        }
        __syncthreads();
        const int tb = sh.bc.wsum[wave] + pre - s;   // exclusive base for bin b4

        if (b4 + 0 < N_BINS) {
            sh.bc.hist[b4 + 0]  = tb;
            sh.bc.gbase[b4 + 0] = c0 ? atomicAdd(&cursor[b4 + 0], c0) : 0;
        }
        if (b4 + 1 < N_BINS) {
            sh.bc.hist[b4 + 1]  = tb + c0;
            sh.bc.gbase[b4 + 1] = c1 ? atomicAdd(&cursor[b4 + 1], c1) : 0;
        }
        if (b4 + 2 < N_BINS) {
            sh.bc.hist[b4 + 2]  = tb + c0 + c1;
            sh.bc.gbase[b4 + 2] = c2 ? atomicAdd(&cursor[b4 + 2], c2) : 0;
        }
        if (b4 + 3 < N_BINS) {
            sh.bc.hist[b4 + 3]  = tb + c0 + c1 + c2;
            sh.bc.gbase[b4 + 3] = c3 ? atomicAdd(&cursor[b4 + 3], c3) : 0;
        }
        __syncthreads();

        // scatter to LDS in bin-sorted order
        #pragma unroll
        for (int k = 0; k < 8; ++k)
            if (bin[k] >= 0)
                sh.bc.sorted[sh.bc.hist[bin[k]] + rk[k]] = make_int2(meta[k], wb[k]);
        __syncthreads();

        // grouped write-out: lanes cover consecutive sorted slots
        const int tot = sh.bc.stot;
        #pragma unroll
        for (int k = 0; k < 8; ++k) {
            int i = t + k * 512;
            if (i < tot) {
                int2 q = sh.bc.sorted[i];
                int b = ((unsigned)q.x) >> 21;          // bin (unsigned shift!)
                int r = i - sh.bc.hist[b];              // rank within (block,bin)
                int g = sh.bc.gbase[b] + r;
                if (g < CAPBIN)
                    entries[(size_t)b * CAPBIN + g] = make_int2(q.x & 0x1FFFFF, q.y);
            }
        }
    } else {
        // ================= gemm1 role: 8 waves, wave owns 64x32 ========
        const int bid2 = blockIdx.x - N_CBLK;
        const int m0 = (bid2 >> 1) * 128;
        const int nhalf = bid2 & 1;              // 0 -> h0, 1 -> ybf
        const int n0r = nhalf * 128;

        const int wm = wave >> 2, wn = wave & 3; // 2 x 4 wave grid
        const int la = lane & 15, kq = lane >> 4;
        const int srow = t >> 3, sc8 = t & 7;    // staging: row 0..63, group 0..7

        f32x4 acc[4][2];
        const f32x4 zero = {0.f, 0.f, 0.f, 0.f};
        #pragma unroll
        for (int i = 0; i < 4; ++i)
            #pragma unroll
            for (int j = 0; j < 2; ++j) acc[i][j] = zero;

        const float4* xg = (const float4*)x;

        for (int kt = 0; kt < 4; ++kt) {
            if (kt) __syncthreads();
            // As[128][64] <- bf16(x rows m0.., cols kt*64..+63), swizzled
            #pragma unroll
            for (int i = 0; i < 2; ++i) {
                int row = srow + i * 64;
                int node = m0 + row;
                float4 v0 = make_float4(0.f, 0.f, 0.f, 0.f), v1 = v0;
                if (node < N_NODES) {
                    v0 = xg[(size_t)node * 64 + kt * 16 + sc8 * 2];
                    v1 = xg[(size_t)node * 64 + kt * 16 + sc8 * 2 + 1];
                }
                u16x8 b;
                b[0] = f2bf(v0.x); b[1] = f2bf(v0.y); b[2] = f2bf(v0.z); b[3] = f2bf(v0.w);
                b[4] = f2bf(v1.x); b[5] = f2bf(v1.y); b[6] = f2bf(v1.z); b[7] = f2bf(v1.w);
                *(u16x8*)&sh.g1.As[row][(sc8 ^ (row & 7)) * 8] = b;
            }
            // Bs[128][64] <- Wcat_t rows n0r..n0r+127, cols kt*64..+63
            #pragma unroll
            for (int i = 0; i < 2; ++i) {
                int row = srow + i * 64;
                float4 v = *(const float4*)(
                    Wcat_t + (size_t)(n0r + row) * IN_FEAT + kt * 64 + sc8 * 8);
                *(float4*)&sh.g1.Bs[row][(sc8 ^ (row & 7)) * 8] = v;
            }
            __syncthreads();

            #pragma unroll
            for (int ks = 0; ks < 2; ++ks) {
                bf16x8 a[4], b[2];
                #pragma unroll
                for (int i = 0; i < 4; ++i) {
                    int row = wm * 64 + i * 16 + la;
                    a[i] = *(const bf16x8*)&sh.g1.As[row][((ks * 4 + kq) ^ (row & 7)) * 8];
                }
                #pragma unroll
                for (int j = 0; j < 2; ++j) {
                    int row = wn * 32 + j * 16 + la;
                    b[j] = *(const bf16x8*)&sh.g1.Bs[row][((ks * 4 + kq) ^ (row & 7)) * 8];
                }
                #pragma unroll
                for (int i = 0; i < 4; ++i)
                    #pragma unroll
                    for (int j = 0; j < 2; ++j)
                        acc[i][j] = __builtin_amdgcn_mfma_f32_16x16x32_bf16(
                            a[i], b[j], acc[i][j], 0, 0, 0);
            }
        }

        float bias[2];
        if (nhalf == 0) {
            #pragma unroll
            for (int j = 0; j < 2; ++j) {
                int n = wn * 32 + j * 16 + la;
                bias[j] = bn[n] + be[n];
            }
        }
        #pragma unroll
        for (int i = 0; i < 4; ++i) {
            int mbase = m0 + wm * 64 + i * 16 + kq * 4;
            #pragma unroll
            for (int j = 0; j < 2; ++j) {
                int n = wn * 32 + j * 16 + la;
                #pragma unroll
                for (int r = 0; r < 4; ++r) {
                    int m = mbase + r;
                    if (m < N_NODES) {
                        if (nhalf == 0)
                            h0[(size_t)m * HID + n] = acc[i][j][r] + bias[j];
                        else
                            ybf[(size_t)m * HID + n] = f2bf(acc[i][j][r]);
                    }
                }
            }
        }
    }
}

// ---------------- fuse2: gather(4 bins) -> LDS A-tile -> GEMM2 -> out -----
// Block b owns rows m0=b*128 == bins 4b..4b+3: purely block-local fusion.
// Gather accumulates w_e*ybf[src] per node, adds h0, writes bf16 into the
// XOR-swizzled LDS A-tile. GEMM reads B-frags directly from L2-resident Wmt.
__global__ __launch_bounds__(512, 4) void fuse2(
    const unsigned short* __restrict__ ybf, const float* __restrict__ h0,
    const int* __restrict__ cursor, const int2* __restrict__ entries,
    const unsigned short* __restrict__ Wmt, const float* __restrict__ bm,
    float* __restrict__ out)
{
    __shared__ unsigned short As[128][128];   // 32 KB swizzled h-tile (bf16)
    __shared__ int2 sorted[CAPBIN];           // 12 KB
    __shared__ int  cnt32[BIN_SZ];
    __shared__ int  offs32[BIN_SZ];

    const int t = threadIdx.x;
    const int wave = t >> 6, lane = t & 63;
    const int m0 = blockIdx.x * 128;
    const int bin0 = blockIdx.x * 4;

    for (int sb = 0; sb < 4; ++sb) {
        const int bin = bin0 + sb;
        const int tot = (bin < N_BINS) ? min(cursor[bin], CAPBIN) : 0;
        if (t < BIN_SZ) cnt32[t] = 0;
        __syncthreads();

        // pass A: rank entries within dst node
        int2 held[3];
        int  hrank[3], hdloc[3];
        #pragma unroll
        for (int k = 0; k < 3; ++k) {
            hdloc[k] = -1;
            int g = t + k * 512;
            if (g < tot) {
                int2 ep = entries[(size_t)bin * CAPBIN + g];
                int dloc = ep.x >> 16;
                held[k]  = make_int2(ep.x & 0xFFFF, ep.y);
                hdloc[k] = dloc;
                hrank[k] = atomicAdd(&cnt32[dloc], 1);
            }
        }
        __syncthreads();

        if (wave == 0) {
            int v = (lane < BIN_SZ) ? cnt32[lane] : 0;
            int sum = v;
            #pragma unroll
            for (int off = 1; off < BIN_SZ; off <<= 1) {
                int o = __shfl_up(sum, off, 64);
                if (lane >= off) sum += o;
            }
            if (lane < BIN_SZ) offs32[lane] = sum - v;
        }
        __syncthreads();

        #pragma unroll
        for (int k = 0; k < 3; ++k)
            if (hdloc[k] >= 0)
                sorted[offs32[hdloc[k]] + hrank[k]] = held[k];
        __syncthreads();

        // gather: 8 waves x 4 nodes; unroll-8 = 8 chains in flight
        #pragma unroll
        for (int n4 = 0; n4 < 4; ++n4) {
            const int nl = wave * 4 + n4;
            const int row = sb * 32 + nl;
            const int node = bin * BIN_SZ + nl;
            const int beg = offs32[nl];
            const int c = cnt32[nl];
            float a0 = 0.f, a1 = 0.f;
            int j = 0;
            for (; j + 8 <= c; j += 8) {
                int2 q[8]; unsigned u[8];
                #pragma unroll
                for (int e = 0; e < 8; ++e) q[e] = sorted[beg + j + e];
                #pragma unroll
                for (int e = 0; e < 8; ++e)
                    u[e] = *(const unsigned*)&ybf[(size_t)q[e].x * HID + 2 * lane];
                #pragma unroll
                for (int e = 0; e < 8; ++e) {
                    float wq = __int_as_float(q[e].y);
                    a0 += wq * bflo(u[e]); a1 += wq * bfhi(u[e]);
                }
            }
            for (; j < c; ++j) {
                int2 q = sorted[beg + j];
                unsigned u = *(const unsigned*)&ybf[(size_t)q.x * HID + 2 * lane];
                float wq = __int_as_float(q.y);
                a0 += wq * bflo(u); a1 += wq * bfhi(u);
            }
            float2 hv = make_float2(0.f, 0.f);
            if (node < N_NODES)
                hv = *(const float2*)&h0[(size_t)node * HID + 2 * lane];
            unsigned rp = ((unsigned)f2bf(hv.y + a1) << 16)
                        | (unsigned)f2bf(hv.x + a0);
            int g8 = (lane >> 2) ^ (row & 7);        // swizzled 16B group
            *(unsigned*)((char*)&As[row][0] + g8 * 16 + (lane & 3) * 4) = rp;
        }
        __syncthreads();
    }

    // GEMM: out[m0..+127][0..255] = As @ Wmt^T + bm
    const int wm = wave >> 2, wn = wave & 3;     // 2 x 4 wave grid
    const int la = lane & 15, kq = lane >> 4;

    f32x4 acc[4][4];
    const f32x4 zero = {0.f, 0.f, 0.f, 0.f};
    #pragma unroll
    for (int i = 0; i < 4; ++i)
        #pragma unroll
        for (int j = 0; j < 4; ++j) acc[i][j] = zero;

    #pragma unroll
    for (int ks = 0; ks < 4; ++ks) {
        bf16x8 a[4], b[4];
        #pragma unroll
        for (int i = 0; i < 4; ++i) {
            int row = wm * 64 + i * 16 + la;
            a[i] = *(const bf16x8*)&As[row][((ks * 4 + kq) ^ (row & 7)) * 8];
        }
        #pragma unroll
        for (int j = 0; j < 4; ++j) {
            int n = wn * 64 + j * 16 + la;
            b[j] = *(const bf16x8*)(Wmt + (size_t)n * HID + ks * 32 + kq * 8);
        }
        #pragma unroll
        for (int i = 0; i < 4; ++i)
            #pragma unroll
            for (int j = 0; j < 4; ++j)
                acc[i][j] = __builtin_amdgcn_mfma_f32_16x16x32_bf16(
                    a[i], b[j], acc[i][j], 0, 0, 0);
    }

    #pragma unroll
    for (int i = 0; i < 4; ++i) {
        int mbase = m0 + wm * 64 + i * 16 + kq * 4;
        #pragma unroll
        for (int j = 0; j < 4; ++j) {
            int n = wn * 64 + j * 16 + la;
            float bv = bm[n];
            #pragma unroll
            for (int r = 0; r < 4; ++r) {
                int m = mbase + r;
                if (m < N_NODES)
                    out[(size_t)m * OUT_FEAT + n] = acc[i][j][r] + bv;
            }
        }
    }
}

extern "C" void kernel_launch(void* const* d_in, const int* in_sizes, int n_in,
                              void* d_out, int out_size, void* d_ws, size_t ws_size,
                              hipStream_t stream) {
    const float* x   = (const float*)d_in[0];
    const float* w   = (const float*)d_in[1];
    const int*   src = (const int*)d_in[2];
    const int*   dst = (const int*)d_in[3];
    const float* Wn  = (const float*)d_in[4];
    const float* bn  = (const float*)d_in[5];
    const float* We  = (const float*)d_in[6];
    const float* be  = (const float*)d_in[7];
    const float* Wm  = (const float*)d_in[8];
    const float* bm  = (const float*)d_in[9];
    float* out = (float*)d_out;

    char* p = (char*)d_ws;
    float*          h0      = (float*)p;          p += (size_t)N_NODES * HID * 4;        // 25.6 MB
    unsigned short* ybf     = (unsigned short*)p; p += (size_t)N_NODES * HID * 2;        // 12.8 MB
    int2*           entries = (int2*)p;           p += (size_t)N_BINS * CAPBIN * 8;      // 19.2 MB
    unsigned short* Wcat_t  = (unsigned short*)p; p += (size_t)256 * IN_FEAT * 2;        // 128 KB
    unsigned short* Wmt     = (unsigned short*)p; p += (size_t)OUT_FEAT * HID * 2;       // 64 KB
    int*            cursor  = (int*)p;            p += (size_t)N_BINS * 4;               // 6.3 KB

    dim3 blk(256);

    hipMemsetAsync(cursor, 0, (size_t)N_BINS * 4, stream);
    k0_convert<<<256, blk, 0, stream>>>(Wn, We, Wm, Wcat_t, Wmt);
    fuse1<<<N_CBLK + N_G1BLK, dim3(512), 0, stream>>>(
        src, dst, w, cursor, entries, x, Wcat_t, bn, be, h0, ybf);
    fuse2<<<GRID_M, dim3(512), 0, stream>>>(ybf, h0, cursor, entries, Wmt, bm, out);
}

// Round 6
// 267.357 us; speedup vs baseline: 1.0133x; 1.0133x over previous
//
#include <hip/hip_runtime.h>

// SmoothGCN: out = ((x@Wn + bn) + (segsum(x[src]*w, dst)@We + be)) @ Wm + bm
// Refactor: y = x@We; h = x@Wn + bn + be; h[dst] += w_e*y[src]; out = h@Wm + bm
// R12: R11's fuse2 (391 blocks) cut gather TLP 4x -- the gather is a
// latency-bound 2-level chain (ds_read -> random 256B ybf row, L2-missing:
// FETCH 162MB) and needs gatherB's 1563-block parallelism. fuse2 now fuses
// at PER-BIN granularity: block b = bin b (1563 blocks), gathers 32 nodes
// exactly like gatherB, writes the 32x128 h-tile to an 8KB swizzled LDS
// tile, then a tiny M=32 GEMM vs L2-resident Wmt -> out. hbf + gemm2 stay
// eliminated; LDS 20.5KB -> thread-capped 4 blocks/CU.

constexpr int N_NODES  = 50000;
constexpr int N_EDGES  = 1600000;
constexpr int IN_FEAT  = 256;
constexpr int HID      = 128;
constexpr int OUT_FEAT = 256;

constexpr int BIN_SZ   = 32;                                // nodes per bin
constexpr int N_BINS   = (N_NODES + BIN_SZ - 1) / BIN_SZ;   // 1563
constexpr int CAPBIN   = 1536;   // mean 1024, multinomial max ~1150, P(>1536)~0
constexpr int EPB      = 4096;   // edges per binC block
constexpr int N_CBLK   = (N_EDGES + EPB - 1) / EPB;         // 391
constexpr int GRID_M   = (N_NODES + 127) / 128;             // 391
constexpr int N_G1BLK  = GRID_M * 2;                        // 782

typedef __attribute__((ext_vector_type(8))) short bf16x8;
typedef __attribute__((ext_vector_type(8))) unsigned short u16x8;
typedef __attribute__((ext_vector_type(4))) float f32x4;

static __device__ __forceinline__ unsigned short f2bf(float f) {
    unsigned u = __builtin_bit_cast(unsigned, f);
    u += 0x7FFF + ((u >> 16) & 1);          // round-to-nearest-even
    return (unsigned short)(u >> 16);
}
static __device__ __forceinline__ float bflo(unsigned u) {
    return __builtin_bit_cast(float, u << 16);
}
static __device__ __forceinline__ float bfhi(unsigned u) {
    return __builtin_bit_cast(float, u & 0xFFFF0000u);
}

// ---------------- k0: transpose+convert weights to bf16 ----------------
__global__ __launch_bounds__(256) void k0_convert(
    const float* __restrict__ Wn, const float* __restrict__ We,
    const float* __restrict__ Wm,
    unsigned short* __restrict__ Wcat_t, unsigned short* __restrict__ Wmt)
{
    int n = blockIdx.x;      // 0..255
    int k = threadIdx.x;     // 0..255
    float v = (n < HID) ? Wn[(size_t)k * HID + n] : We[(size_t)k * HID + (n - HID)];
    Wcat_t[(size_t)n * IN_FEAT + k] = f2bf(v);
    if (k < HID) Wmt[(size_t)n * HID + k] = f2bf(Wm[(size_t)k * OUT_FEAT + n]);
}

// ---------------- fuse1: binC (blocks 0..N_CBLK-1) || gemm1 (rest) --------
union SharedU {
    struct {
        int  hist[N_BINS];
        int  gbase[N_BINS];
        int  wsum[8];
        int  stot;
        int2 sorted[EPB];            // 32 KB
    } bc;                            // ~44.3 KB
    struct {
        unsigned short As[128][64];  // 16 KB
        unsigned short Bs[128][64];  // 16 KB
    } g1;
};

__global__ __launch_bounds__(512, 4) void fuse1(
    const int* __restrict__ src, const int* __restrict__ dst,
    const float* __restrict__ w, int* __restrict__ cursor,
    int2* __restrict__ entries,
    const float* __restrict__ x, const unsigned short* __restrict__ Wcat_t,
    const float* __restrict__ bn, const float* __restrict__ be,
    float* __restrict__ h0, unsigned short* __restrict__ ybf)
{
    __shared__ SharedU sh;
    const int t = threadIdx.x;
    const int wave = t >> 6, lane = t & 63;

    if (blockIdx.x < N_CBLK) {
        // ================= binC role (unchanged logic) =================
        const int e0 = blockIdx.x * EPB;

        for (int i = t; i < N_BINS; i += 512) sh.bc.hist[i] = 0;
        __syncthreads();

        int meta[8], wb[8], rk[8], bin[8];
        #pragma unroll
        for (int k = 0; k < 8; ++k) {
            int e = e0 + t + k * 512;
            bin[k] = -1;
            if (e < N_EDGES) {
                int d = dst[e];
                int b = d >> 5;
                bin[k]  = b;
                meta[k] = src[e] | ((d & 31) << 16) | (b << 21);  // src<65536 ok
                wb[k]   = __float_as_int(w[e]);
                rk[k]   = atomicAdd(&sh.bc.hist[b], 1);
            }
        }
        __syncthreads();

        // block exclusive scan of hist (4 contiguous bins per thread)
        const int b4 = t * 4;
        int c0 = 0, c1 = 0, c2 = 0, c3 = 0;
        if (b4 + 0 < N_BINS) c0 = sh.bc.hist[b4 + 0];
        if (b4 + 1 < N_BINS) c1 = sh.bc.hist[b4 + 1];
        if (b4 + 2 < N_BINS) c2 = sh.bc.hist[b4 + 2];
        if (b4 + 3 < N_BINS) c3 = sh.bc.hist[b4 + 3];
        const int s = c0 + c1 + c2 + c3;
        int pre = s;
        #pragma unroll
        for (int off = 1; off < 64; off <<= 1) {
            int o = __shfl_up(pre, off, 64);
            if (lane >= off) pre += o;
        }
        if (lane == 63) sh.bc.wsum[wave] = pre;
        __syncthreads();
        if (t == 0) {
            int r = 0;
            #pragma unroll
            for (int q = 0; q < 8; ++q) { int v = sh.bc.wsum[q]; sh.bc.wsum[q] = r; r += v; }
            sh.bc.stot = r;
        }
        __syncthreads();
        const int tb = sh.bc.wsum[wave] + pre - s;   // exclusive base for bin b4

        if (b4 + 0 < N_BINS) {
            sh.bc.hist[b4 + 0]  = tb;
            sh.bc.gbase[b4 + 0] = c0 ? atomicAdd(&cursor[b4 + 0], c0) : 0;
        }
        if (b4 + 1 < N_BINS) {
            sh.bc.hist[b4 + 1]  = tb + c0;
            sh.bc.gbase[b4 + 1] = c1 ? atomicAdd(&cursor[b4 + 1], c1) : 0;
        }
        if (b4 + 2 < N_BINS) {
            sh.bc.hist[b4 + 2]  = tb + c0 + c1;
            sh.bc.gbase[b4 + 2] = c2 ? atomicAdd(&cursor[b4 + 2], c2) : 0;
        }
        if (b4 + 3 < N_BINS) {
            sh.bc.hist[b4 + 3]  = tb + c0 + c1 + c2;
            sh.bc.gbase[b4 + 3] = c3 ? atomicAdd(&cursor[b4 + 3], c3) : 0;
        }
        __syncthreads();

        // scatter to LDS in bin-sorted order
        #pragma unroll
        for (int k = 0; k < 8; ++k)
            if (bin[k] >= 0)
                sh.bc.sorted[sh.bc.hist[bin[k]] + rk[k]] = make_int2(meta[k], wb[k]);
        __syncthreads();

        // grouped write-out: lanes cover consecutive sorted slots
        const int tot = sh.bc.stot;
        #pragma unroll
        for (int k = 0; k < 8; ++k) {
            int i = t + k * 512;
            if (i < tot) {
                int2 q = sh.bc.sorted[i];
                int b = ((unsigned)q.x) >> 21;          // bin (unsigned shift!)
                int r = i - sh.bc.hist[b];              // rank within (block,bin)
                int g = sh.bc.gbase[b] + r;
                if (g < CAPBIN)
                    entries[(size_t)b * CAPBIN + g] = make_int2(q.x & 0x1FFFFF, q.y);
            }
        }
    } else {
        // ================= gemm1 role: 8 waves, wave owns 64x32 ========
        const int bid2 = blockIdx.x - N_CBLK;
        const int m0 = (bid2 >> 1) * 128;
        const int nhalf = bid2 & 1;              // 0 -> h0, 1 -> ybf
        const int n0r = nhalf * 128;

        const int wm = wave >> 2, wn = wave & 3; // 2 x 4 wave grid
        const int la = lane & 15, kq = lane >> 4;
        const int srow = t >> 3, sc8 = t & 7;    // staging: row 0..63, group 0..7

        f32x4 acc[4][2];
        const f32x4 zero = {0.f, 0.f, 0.f, 0.f};
        #pragma unroll
        for (int i = 0; i < 4; ++i)
            #pragma unroll
            for (int j = 0; j < 2; ++j) acc[i][j] = zero;

        const float4* xg = (const float4*)x;

        for (int kt = 0; kt < 4; ++kt) {
            if (kt) __syncthreads();
            // As[128][64] <- bf16(x rows m0.., cols kt*64..+63), swizzled
            #pragma unroll
            for (int i = 0; i < 2; ++i) {
                int row = srow + i * 64;
                int node = m0 + row;
                float4 v0 = make_float4(0.f, 0.f, 0.f, 0.f), v1 = v0;
                if (node < N_NODES) {
                    v0 = xg[(size_t)node * 64 + kt * 16 + sc8 * 2];
                    v1 = xg[(size_t)node * 64 + kt * 16 + sc8 * 2 + 1];
                }
                u16x8 b;
                b[0] = f2bf(v0.x); b[1] = f2bf(v0.y); b[2] = f2bf(v0.z); b[3] = f2bf(v0.w);
                b[4] = f2bf(v1.x); b[5] = f2bf(v1.y); b[6] = f2bf(v1.z); b[7] = f2bf(v1.w);
                *(u16x8*)&sh.g1.As[row][(sc8 ^ (row & 7)) * 8] = b;
            }
            // Bs[128][64] <- Wcat_t rows n0r..n0r+127, cols kt*64..+63
            #pragma unroll
            for (int i = 0; i < 2; ++i) {
                int row = srow + i * 64;
                float4 v = *(const float4*)(
                    Wcat_t + (size_t)(n0r + row) * IN_FEAT + kt * 64 + sc8 * 8);
                *(float4*)&sh.g1.Bs[row][(sc8 ^ (row & 7)) * 8] = v;
            }
            __syncthreads();

            #pragma unroll
            for (int ks = 0; ks < 2; ++ks) {
                bf16x8 a[4], b[2];
                #pragma unroll
                for (int i = 0; i < 4; ++i) {
                    int row = wm * 64 + i * 16 + la;
                    a[i] = *(const bf16x8*)&sh.g1.As[row][((ks * 4 + kq) ^ (row & 7)) * 8];
                }
                #pragma unroll
                for (int j = 0; j < 2; ++j) {
                    int row = wn * 32 + j * 16 + la;
                    b[j] = *(const bf16x8*)&sh.g1.Bs[row][((ks * 4 + kq) ^ (row & 7)) * 8];
                }
                #pragma unroll
                for (int i = 0; i < 4; ++i)
                    #pragma unroll
                    for (int j = 0; j < 2; ++j)
                        acc[i][j] = __builtin_amdgcn_mfma_f32_16x16x32_bf16(
                            a[i], b[j], acc[i][j], 0, 0, 0);
            }
        }

        float bias[2];
        if (nhalf == 0) {
            #pragma unroll
            for (int j = 0; j < 2; ++j) {
                int n = wn * 32 + j * 16 + la;
                bias[j] = bn[n] + be[n];
            }
        }
        #pragma unroll
        for (int i = 0; i < 4; ++i) {
            int mbase = m0 + wm * 64 + i * 16 + kq * 4;
            #pragma unroll
            for (int j = 0; j < 2; ++j) {
                int n = wn * 32 + j * 16 + la;
                #pragma unroll
                for (int r = 0; r < 4; ++r) {
                    int m = mbase + r;
                    if (m < N_NODES) {
                        if (nhalf == 0)
                            h0[(size_t)m * HID + n] = acc[i][j][r] + bias[j];
                        else
                            ybf[(size_t)m * HID + n] = f2bf(acc[i][j][r]);
                    }
                }
            }
        }
    }
}

// ---------------- fuse2: per-bin gather -> 8KB LDS tile -> M=32 GEMM ------
// Block = bin (1563 blocks, gatherB's TLP). Gather identical to gatherB;
// h-row goes to swizzled LDS instead of hbf; then 16 MFMA/wave vs Wmt.
__global__ __launch_bounds__(512, 4) void fuse2(
    const unsigned short* __restrict__ ybf, const float* __restrict__ h0,
    const int* __restrict__ cursor, const int2* __restrict__ entries,
    const unsigned short* __restrict__ Wmt, const float* __restrict__ bm,
    float* __restrict__ out)
{
    __shared__ int2 sorted[CAPBIN];           // 12 KB
    __shared__ unsigned short As[32][128];    // 8 KB swizzled h-tile (bf16)
    __shared__ int  cnt32[BIN_SZ];
    __shared__ int  offs32[BIN_SZ];

    const int t = threadIdx.x;
    const int wave = t >> 6, lane = t & 63;
    const int bin = blockIdx.x;
    const int node0 = bin * BIN_SZ;

    const int tot = min(cursor[bin], CAPBIN);
    if (t < BIN_SZ) cnt32[t] = 0;
    __syncthreads();

    // pass A: read my <=3 entries (coalesced, dense), rank within dst node
    int2 held[3];
    int  hrank[3], hdloc[3];
    #pragma unroll
    for (int k = 0; k < 3; ++k) {
        hdloc[k] = -1;
        int g = t + k * 512;
        if (g < tot) {
            int2 ep = entries[(size_t)bin * CAPBIN + g];
            int dloc = ep.x >> 16;
            held[k]  = make_int2(ep.x & 0xFFFF, ep.y);
            hdloc[k] = dloc;
            hrank[k] = atomicAdd(&cnt32[dloc], 1);
        }
    }
    __syncthreads();

    // scan cnt32 -> offs32 (wave 0)
    if (wave == 0) {
        int v = (lane < BIN_SZ) ? cnt32[lane] : 0;
        int sum = v;
        #pragma unroll
        for (int off = 1; off < BIN_SZ; off <<= 1) {
            int o = __shfl_up(sum, off, 64);
            if (lane >= off) sum += o;
        }
        if (lane < BIN_SZ) offs32[lane] = sum - v;
    }
    __syncthreads();

    // pass B: scatter to node-sorted order
    #pragma unroll
    for (int k = 0; k < 3; ++k)
        if (hdloc[k] >= 0)
            sorted[offs32[hdloc[k]] + hrank[k]] = held[k];
    __syncthreads();

    // gather: 8 waves x 4 nodes, unroll-8 = 8 load chains in flight
    #pragma unroll
    for (int n4 = 0; n4 < 4; ++n4) {
        const int nl = wave * 4 + n4;
        const int node = node0 + nl;
        const int beg = offs32[nl];
        const int c = cnt32[nl];
        float a0 = 0.f, a1 = 0.f;
        int j = 0;
        for (; j + 8 <= c; j += 8) {
            int2 q[8]; unsigned u[8];
            #pragma unroll
            for (int e = 0; e < 8; ++e) q[e] = sorted[beg + j + e];
            #pragma unroll
            for (int e = 0; e < 8; ++e)
                u[e] = *(const unsigned*)&ybf[(size_t)q[e].x * HID + 2 * lane];
            #pragma unroll
            for (int e = 0; e < 8; ++e) {
                float wq = __int_as_float(q[e].y);
                a0 += wq * bflo(u[e]); a1 += wq * bfhi(u[e]);
            }
        }
        for (; j < c; ++j) {
            int2 q = sorted[beg + j];
            unsigned u = *(const unsigned*)&ybf[(size_t)q.x * HID + 2 * lane];
            float wq = __int_as_float(q.y);
            a0 += wq * bflo(u); a1 += wq * bfhi(u);
        }
        float2 hv = make_float2(0.f, 0.f);
        if (node < N_NODES)
            hv = *(const float2*)&h0[(size_t)node * HID + 2 * lane];
        unsigned rp = ((unsigned)f2bf(hv.y + a1) << 16)
                    | (unsigned)f2bf(hv.x + a0);
        int g8 = (lane >> 2) ^ (nl & 7);          // swizzled 16B group (of 16)
        *(unsigned*)((char*)&As[nl][0] + g8 * 16 + (lane & 3) * 4) = rp;
    }
    __syncthreads();

    // GEMM: out[node0..+31][0..255] = As @ Wmt^T + bm
    const int wm = wave >> 2, wn = wave & 3;      // 2 x 4 wave grid
    const int la = lane & 15, kq = lane >> 4;

    f32x4 acc[4];
    const f32x4 zero = {0.f, 0.f, 0.f, 0.f};
    #pragma unroll
    for (int j = 0; j < 4; ++j) acc[j] = zero;

    #pragma unroll
    for (int ks = 0; ks < 4; ++ks) {
        int row = wm * 16 + la;
        bf16x8 a = *(const bf16x8*)&As[row][(((ks * 4 + kq) ^ (row & 7))) * 8];
        #pragma unroll
        for (int j = 0; j < 4; ++j) {
            int n = wn * 64 + j * 16 + la;
            bf16x8 b = *(const bf16x8*)(Wmt + (size_t)n * HID + ks * 32 + kq * 8);
            acc[j] = __builtin_amdgcn_mfma_f32_16x16x32_bf16(a, b, acc[j], 0, 0, 0);
        }
    }

    const int mbase = node0 + wm * 16 + kq * 4;
    #pragma unroll
    for (int j = 0; j < 4; ++j) {
        int n = wn * 64 + j * 16 + la;
        float bv = bm[n];
        #pragma unroll
        for (int r = 0; r < 4; ++r) {
            int m = mbase + r;
            if (m < N_NODES)
                out[(size_t)m * OUT_FEAT + n] = acc[j][r] + bv;
        }
    }
}

extern "C" void kernel_launch(void* const* d_in, const int* in_sizes, int n_in,
                              void* d_out, int out_size, void* d_ws, size_t ws_size,
                              hipStream_t stream) {
    const float* x   = (const float*)d_in[0];
    const float* w   = (const float*)d_in[1];
    const int*   src = (const int*)d_in[2];
    const int*   dst = (const int*)d_in[3];
    const float* Wn  = (const float*)d_in[4];
    const float* bn  = (const float*)d_in[5];
    const float* We  = (const float*)d_in[6];
    const float* be  = (const float*)d_in[7];
    const float* Wm  = (const float*)d_in[8];
    const float* bm  = (const float*)d_in[9];
    float* out = (float*)d_out;

    char* p = (char*)d_ws;
    float*          h0      = (float*)p;          p += (size_t)N_NODES * HID * 4;        // 25.6 MB
    unsigned short* ybf     = (unsigned short*)p; p += (size_t)N_NODES * HID * 2;        // 12.8 MB
    int2*           entries = (int2*)p;           p += (size_t)N_BINS * CAPBIN * 8;      // 19.2 MB
    unsigned short* Wcat_t  = (unsigned short*)p; p += (size_t)256 * IN_FEAT * 2;        // 128 KB
    unsigned short* Wmt     = (unsigned short*)p; p += (size_t)OUT_FEAT * HID * 2;       // 64 KB
    int*            cursor  = (int*)p;            p += (size_t)N_BINS * 4;               // 6.3 KB

    dim3 blk(256);

    hipMemsetAsync(cursor, 0, (size_t)N_BINS * 4, stream);
    k0_convert<<<256, blk, 0, stream>>>(Wn, We, Wm, Wcat_t, Wmt);
    fuse1<<<N_CBLK + N_G1BLK, dim3(512), 0, stream>>>(
        src, dst, w, cursor, entries, x, Wcat_t, bn, be, h0, ybf);
    fuse2<<<N_BINS, dim3(512), 0, stream>>>(ybf, h0, cursor, entries, Wmt, bm, out);
}